// Round 11
// baseline (96.272 us; speedup 1.0000x reference)
//
#include <hip/hip_runtime.h>
#include <stdint.h>

#define H_ 224
#define W_ 224
#define NPIX (H_ * W_)          // 50176
#define NQ4 (NPIX / 4)          // 12544 dwords per frame
#define NFRAMES 256
#define NT 512
#define NWAVE 8
#define CHS (8 * NPIX)          // channel stride in floats
#define M10 (223 * 56)          // 12488: dwords with a valid row below

__device__ __forceinline__ uint32_t udot4acc(uint32_t a, uint32_t b, uint32_t c) {
#if __has_builtin(__builtin_amdgcn_udot4)
    return __builtin_amdgcn_udot4(a, b, c, false);
#else
    c += (a & 0xffu) * (b & 0xffu);
    c += ((a >> 8) & 0xffu) * ((b >> 8) & 0xffu);
    c += ((a >> 16) & 0xffu) * ((b >> 16) & 0xffu);
    c += (a >> 24) * (b >> 24);
    return c;
#endif
}

__device__ __forceinline__ uint32_t quant1(float s) {
    float gr = s / 3.0f;
    float v = floorf(gr * 255.0f);
    v = fminf(fmaxf(v, 0.0f), 255.0f);
    return (uint32_t)(int)v;
}

// swizzled u8-packed histogram word index (bank near-uniform for random a)
__device__ __forceinline__ void hist_inc(uint32_t* hist, uint32_t a, uint32_t b) {
    uint32_t w = ((a << 6) | (b >> 2)) ^ (a & 31u);
    atomicAdd(&hist[w], 1u << ((b & 3u) << 3));
}

// ---- stats scan (512 threads): con/dis via udot4 triple + slin + cross ----
__device__ __forceinline__ void stats_scan(const uint32_t* hist, int tid, int wave, int lane,
                                           double invnp, double inv2np2,
                                           double& conD, double& disD,
                                           double& homD, double& asmD) {
    int conI = 0, disI = 0;
    uint32_t slinU = 0;
    float homF = 0.0f;
    #pragma unroll 4
    for (int itr = 0; itr < 32; ++itr) {
        int m = tid + (itr << 9);
        uint32_t w = hist[m];
        if (w) {                                   // empty word-groups skip (execz)
            int i = m >> 6;
            int c4 = (m & 63) ^ (i & 31);          // undo swizzle: col group
            int d0 = i - (c4 << 2);                // d for k=0
            slinU = udot4acc(w, w, slinU);
            int sb   = (int)udot4acc(w, 0x01010101u, 0u);
            int skb  = (int)udot4acc(w, 0x03020100u, 0u);
            int sk2b = (int)udot4acc(w, 0x09040100u, 0u);
            conI += d0 * d0 * sb - 2 * d0 * skb + sk2b;
            if (d0 == 1 || d0 == 2) {              // mixed-sign |d|: exact path
                int t = 0;
                #pragma unroll
                for (int k = 0; k < 4; ++k) {
                    int d = d0 - k;
                    t += (int)((w >> (k << 3)) & 0xffu) * (d < 0 ? -d : d);
                }
                disI += t;
            } else {
                int t = d0 * sb - skb;             // uniform sign
                disI += (t < 0) ? -t : t;
            }
            #pragma unroll
            for (int k = 0; k < 4; ++k) {
                uint32_t bv = (w >> (k << 3)) & 0xffu;
                int d = d0 - k;
                homF += (float)bv * __builtin_amdgcn_rcpf(1.0f + (float)(d * d));
            }
        }
    }

    // cross term sum h_ij * h_ji over 4x4 byte tiles; s = wave + 8q covers 0..63
    uint32_t scrU = 0;
    #pragma unroll
    for (int q = 0; q < 8; ++q) {
        int s = wave + (q << 3);
        int jt = (lane + s) & 63;
        uint32_t A[4], Bw[4];
        #pragma unroll
        for (int k = 0; k < 4; ++k) {
            int ia = 4 * lane + k;
            A[k]  = hist[((ia << 6) | jt)   ^ (ia & 31)];
            int ib = 4 * jt + k;
            Bw[k] = hist[((ib << 6) | lane) ^ (ib & 31)];
        }
        if ((A[0] | A[1] | A[2] | A[3]) && (Bw[0] | Bw[1] | Bw[2] | Bw[3])) {
            uint32_t x0 = __builtin_amdgcn_perm(Bw[1], Bw[0], 0x05010400u);
            uint32_t x1 = __builtin_amdgcn_perm(Bw[1], Bw[0], 0x07030602u);
            uint32_t x2 = __builtin_amdgcn_perm(Bw[3], Bw[2], 0x05010400u);
            uint32_t x3 = __builtin_amdgcn_perm(Bw[3], Bw[2], 0x07030602u);
            uint32_t t0 = __builtin_amdgcn_perm(x2, x0, 0x05040100u);
            uint32_t t1 = __builtin_amdgcn_perm(x2, x0, 0x07060302u);
            uint32_t t2 = __builtin_amdgcn_perm(x3, x1, 0x05040100u);
            uint32_t t3 = __builtin_amdgcn_perm(x3, x1, 0x07060302u);
            scrU = udot4acc(A[0], t0, scrU);
            scrU = udot4acc(A[1], t1, scrU);
            scrU = udot4acc(A[2], t2, scrU);
            scrU = udot4acc(A[3], t3, scrU);
        }
    }

    conD += (double)conI * invnp;
    disD += (double)disI * invnp;
    homD += (double)homF * invnp;
    asmD += ((double)slinU + (double)scrU) * inv2np2;
}

// ---------------- fused kernel: one frame per block, 2 blocks/CU ----------------
__global__ __launch_bounds__(NT, 4) void k_fused(const float* __restrict__ x,
                                                 uint32_t* __restrict__ gray,
                                                 float* __restrict__ out) {
    __shared__ uint32_t hist[16384];    // 64 KB u8 H[256][256], swizzled words
    __shared__ double red[64];

    const int f = blockIdx.x;
    const int bq = f >> 3, fq = f & 7;
    const int tid = threadIdx.x, lane = tid & 63, wave = tid >> 6;

    const float4* xc0 = reinterpret_cast<const float4*>(x + ((size_t)bq * 24 + fq) * NPIX);
    const float4* xc1 = reinterpret_cast<const float4*>(x + ((size_t)bq * 24 + fq) * NPIX + CHS);
    const float4* xc2 = reinterpret_cast<const float4*>(x + ((size_t)bq * 24 + fq) * NPIX + 2 * CHS);
    uint32_t* gg = gray + (size_t)f * NQ4;

    uint4* h4 = reinterpret_cast<uint4*>(hist);
    const uint4 z4 = make_uint4(0u, 0u, 0u, 0u);
    #pragma unroll
    for (int i = 0; i < 8; ++i) h4[tid + (i << 9)] = z4;
    __syncthreads();

    // ---- stream: load x, quantize, gray write, std + (0,1) atomics fused ----
    uint32_t s1 = 0, s2 = 0;
    for (int m = tid; m < NQ4; m += NT) {          // last iter = waves 0..3, full waves
        float4 av = xc0[m], bv = xc1[m], cv = xc2[m];
        uint32_t v0 = quant1(av.x + bv.x + cv.x);
        uint32_t v1 = quant1(av.y + bv.y + cv.y);
        uint32_t v2 = quant1(av.z + bv.z + cv.z);
        uint32_t v3 = quant1(av.w + bv.w + cv.w);
        uint32_t pk = v0 | (v1 << 8) | (v2 << 16) | (v3 << 24);
        gg[m] = pk;
        s1 = udot4acc(pk, 0x01010101u, s1);
        s2 = udot4acc(pk, pk, s2);
        uint32_t nx = __shfl_down(pk, 1, 64);
        hist_inc(hist, pk & 0xffu, (pk >> 8) & 0xffu);
        hist_inc(hist, (pk >> 8) & 0xffu, (pk >> 16) & 0xffu);
        hist_inc(hist, (pk >> 16) & 0xffu, pk >> 24);
        if (lane != 63 && m % 56 != 55)
            hist_inc(hist, pk >> 24, nx & 0xffu);
    }
    __syncthreads();                               // drains vmcnt: gray visible to block

    // deferred lane-63 cross-dword (0,1) pairs (read own-written gray)
    if (tid < 196) {
        int m = tid * 64 + 63;
        if (m % 56 != 55) hist_inc(hist, gg[m] >> 24, gg[m + 1] & 0xffu);
    }
    __syncthreads();

    double conD = 0.0, disD = 0.0, homD = 0.0, asmD = 0.0;
    const double npA = 49952.0, npB = 49729.0;
    const double invA = 1.0 / npA, invB = 1.0 / npB;
    const double invA2 = 1.0 / (2.0 * npA * npA), invB2 = 1.0 / (2.0 * npB * npB);

    stats_scan(hist, tid, wave, lane, invA, invA2, conD, disD, homD, asmD);   // (0,1)
    __syncthreads();

    // ---- offset (1,1) ----
    #pragma unroll
    for (int i = 0; i < 8; ++i) h4[tid + (i << 9)] = z4;
    __syncthreads();
    for (int it = 0; it < 25; ++it) {
        int m = it * NT + tid;
        int mc = (m < M10) ? m : (M10 - 1);        // clamp keeps shfl sources exact
        uint32_t A = gg[mc];
        uint32_t B = gg[mc + 56];
        uint32_t Bn = __shfl_down(B, 1, 64);
        uint32_t Bv = (B >> 8) | (Bn << 24);
        if (m < M10) {
            hist_inc(hist, A & 0xffu, Bv & 0xffu);
            hist_inc(hist, (A >> 8) & 0xffu, (Bv >> 8) & 0xffu);
            hist_inc(hist, (A >> 16) & 0xffu, (Bv >> 16) & 0xffu);
            if (lane != 63 && m % 56 != 55)
                hist_inc(hist, A >> 24, Bv >> 24);
        }
    }
    if (tid < 195) {                               // lane-63 boundary fixup
        int m = tid * 64 + 63;
        if (m < M10 && m % 56 != 55)
            hist_inc(hist, gg[m] >> 24, gg[m + 57] & 0xffu);
    }
    __syncthreads();
    stats_scan(hist, tid, wave, lane, invB, invB2, conD, disD, homD, asmD);
    __syncthreads();

    // ---- offset (1,0) ----
    #pragma unroll
    for (int i = 0; i < 8; ++i) h4[tid + (i << 9)] = z4;
    __syncthreads();
    for (int it = 0; it < 25; ++it) {
        int m = it * NT + tid;
        if (m < M10) {
            uint32_t A = gg[m];
            uint32_t B = gg[m + 56];
            #pragma unroll
            for (int k = 0; k < 4; ++k)
                hist_inc(hist, (A >> (8 * k)) & 0xffu, (B >> (8 * k)) & 0xffu);
        }
    }
    __syncthreads();
    stats_scan(hist, tid, wave, lane, invA, invA2, conD, disD, homD, asmD);
    __syncthreads();

    // ---- offset (1,-1) ----
    #pragma unroll
    for (int i = 0; i < 8; ++i) h4[tid + (i << 9)] = z4;
    __syncthreads();
    for (int it = 0; it < 25; ++it) {
        int m = it * NT + tid;
        int mc = (m < M10) ? m : (M10 - 1);
        uint32_t A = gg[mc];
        uint32_t B = gg[mc + 56];
        uint32_t Bp = __shfl_up(B, 1, 64);
        uint32_t Bv = (B << 8) | (Bp >> 24);
        if (m < M10) {
            if (lane != 0 && m % 56 != 0)
                hist_inc(hist, A & 0xffu, Bv & 0xffu);
            hist_inc(hist, (A >> 8) & 0xffu, (Bv >> 8) & 0xffu);
            hist_inc(hist, (A >> 16) & 0xffu, (Bv >> 16) & 0xffu);
            hist_inc(hist, A >> 24, Bv >> 24);
        }
    }
    if (tid >= 1 && tid < 196) {                   // lane-0 boundary fixup
        int m = tid * 64;
        if (m < M10 && m % 56 != 0)
            hist_inc(hist, gg[m] & 0xffu, gg[m + 55] >> 24);
    }
    __syncthreads();
    stats_scan(hist, tid, wave, lane, invB, invB2, conD, disD, homD, asmD);

    // ---- fused reduction of 6 doubles, finalize ----
    double vals[6] = {(double)s1, (double)s2, conD, disD, homD, asmD};
    #pragma unroll
    for (int off = 32; off; off >>= 1) {
        #pragma unroll
        for (int i = 0; i < 6; ++i) vals[i] += __shfl_down(vals[i], off, 64);
    }
    if (lane == 0) {
        #pragma unroll
        for (int i = 0; i < 6; ++i) red[wave * 8 + i] = vals[i];
    }
    __syncthreads();
    if (tid == 0) {
        double acc[6];
        #pragma unroll
        for (int i = 0; i < 6; ++i) {
            double t = red[i];
            for (int w = 1; w < NWAVE; ++w) t += red[w * 8 + i];
            acc[i] = t;
        }
        double N = (double)NPIX;
        double mean = acc[0] / N;
        double var = acc[1] / N - mean * mean;
        if (var < 0.0) var = 0.0;
        float* op = out + f * 6;
        op[0] = (float)sqrt(var);
        op[1] = (float)(acc[2] * 0.25);
        op[2] = (float)(acc[3] * 0.25);
        op[3] = (float)(acc[4] * 0.25);
        op[4] = (float)(acc[5] * 0.25);
        op[5] = (float)sqrt(acc[5] * 0.25);
    }
}

extern "C" void kernel_launch(void* const* d_in, const int* in_sizes, int n_in,
                              void* d_out, int out_size, void* d_ws, size_t ws_size,
                              hipStream_t stream) {
    const float* x = (const float*)d_in[0];
    float* out = (float*)d_out;
    uint32_t* gray = (uint32_t*)d_ws;     // 12,845,056 bytes
    k_fused<<<NFRAMES, NT, 0, stream>>>(x, gray, out);
}

// Round 12
// 80.220 us; speedup vs baseline: 1.2001x; 1.2001x over previous
//
#include <hip/hip_runtime.h>
#include <stdint.h>

#define H_ 224
#define W_ 224
#define NPIX (H_ * W_)          // 50176
#define NQ4 (NPIX / 4)          // 12544 dwords per frame
#define ROWQ 56                 // dwords per row
#define NFRAMES 256
#define NT 512
#define NWAVE 8
#define STRIP 28                // rows per wave in the stream
#define M10 (223 * 56)          // 12488: dwords with a valid row below
#define GRAY_BYTES ((size_t)NFRAMES * NPIX)

__device__ __forceinline__ uint32_t udot4acc(uint32_t a, uint32_t b, uint32_t c) {
#if __has_builtin(__builtin_amdgcn_udot4)
    return __builtin_amdgcn_udot4(a, b, c, false);
#else
    c += (a & 0xffu) * (b & 0xffu);
    c += ((a >> 8) & 0xffu) * ((b >> 8) & 0xffu);
    c += ((a >> 16) & 0xffu) * ((b >> 16) & 0xffu);
    c += (a >> 24) * (b >> 24);
    return c;
#endif
}

__device__ __forceinline__ uint32_t quant1(float s) {
    float gr = s / 3.0f;
    float v = floorf(gr * 255.0f);
    v = fminf(fmaxf(v, 0.0f), 255.0f);
    return (uint32_t)(int)v;
}

// swizzled u8-packed histogram word index (bank near-uniform for random a)
__device__ __forceinline__ void hist_inc(uint32_t* hist, uint32_t a, uint32_t b) {
    uint32_t w = ((a << 6) | (b >> 2)) ^ (a & 31u);
    atomicAdd(&hist[w], 1u << ((b & 3u) << 3));
}

// ---- stats scan (512 threads): con/dis via udot4 triple + slin + cross ----
__device__ __forceinline__ void stats_scan(const uint32_t* hist, int tid, int wave, int lane,
                                           double invnp, double inv2np2,
                                           double& conD, double& disD,
                                           double& homD, double& asmD) {
    int conI = 0, disI = 0;
    uint32_t slinU = 0;
    float homF = 0.0f;
    #pragma unroll 4
    for (int itr = 0; itr < 32; ++itr) {
        int m = tid + (itr << 9);
        uint32_t w = hist[m];
        if (w) {                                   // empty word-groups skip (execz)
            int i = m >> 6;
            int c4 = (m & 63) ^ (i & 31);          // undo swizzle: col group
            int d0 = i - (c4 << 2);                // d for k=0
            slinU = udot4acc(w, w, slinU);
            int sb   = (int)udot4acc(w, 0x01010101u, 0u);
            int skb  = (int)udot4acc(w, 0x03020100u, 0u);
            int sk2b = (int)udot4acc(w, 0x09040100u, 0u);
            conI += d0 * d0 * sb - 2 * d0 * skb + sk2b;
            if (d0 == 1 || d0 == 2) {              // mixed-sign |d|: exact path
                int t = 0;
                #pragma unroll
                for (int k = 0; k < 4; ++k) {
                    int d = d0 - k;
                    t += (int)((w >> (k << 3)) & 0xffu) * (d < 0 ? -d : d);
                }
                disI += t;
            } else {
                int t = d0 * sb - skb;             // uniform sign
                disI += (t < 0) ? -t : t;
            }
            #pragma unroll
            for (int k = 0; k < 4; ++k) {
                uint32_t bv = (w >> (k << 3)) & 0xffu;
                int d = d0 - k;
                homF += (float)bv * __builtin_amdgcn_rcpf(1.0f + (float)(d * d));
            }
        }
    }

    // cross term sum h_ij * h_ji over 4x4 byte tiles; s = wave + 8q covers 0..63
    uint32_t scrU = 0;
    #pragma unroll
    for (int q = 0; q < 8; ++q) {
        int s = wave + (q << 3);
        int jt = (lane + s) & 63;
        uint32_t A[4], Bw[4];
        #pragma unroll
        for (int k = 0; k < 4; ++k) {
            int ia = 4 * lane + k;
            A[k]  = hist[((ia << 6) | jt)   ^ (ia & 31)];
            int ib = 4 * jt + k;
            Bw[k] = hist[((ib << 6) | lane) ^ (ib & 31)];
        }
        if ((A[0] | A[1] | A[2] | A[3]) && (Bw[0] | Bw[1] | Bw[2] | Bw[3])) {
            uint32_t x0 = __builtin_amdgcn_perm(Bw[1], Bw[0], 0x05010400u);
            uint32_t x1 = __builtin_amdgcn_perm(Bw[1], Bw[0], 0x07030602u);
            uint32_t x2 = __builtin_amdgcn_perm(Bw[3], Bw[2], 0x05010400u);
            uint32_t x3 = __builtin_amdgcn_perm(Bw[3], Bw[2], 0x07030602u);
            uint32_t t0 = __builtin_amdgcn_perm(x2, x0, 0x05040100u);
            uint32_t t1 = __builtin_amdgcn_perm(x2, x0, 0x07060302u);
            uint32_t t2 = __builtin_amdgcn_perm(x3, x1, 0x05040100u);
            uint32_t t3 = __builtin_amdgcn_perm(x3, x1, 0x07060302u);
            scrU = udot4acc(A[0], t0, scrU);
            scrU = udot4acc(A[1], t1, scrU);
            scrU = udot4acc(A[2], t2, scrU);
            scrU = udot4acc(A[3], t3, scrU);
        }
    }

    conD += (double)conI * invnp;
    disD += (double)disI * invnp;
    homD += (double)homF * invnp;
    asmD += ((double)slinU + (double)scrU) * inv2np2;
}

// ---------------- Kernel 1: (frame, half) per block; 512 blocks; 2/CU ----------------
// half0: stream + fused std + (0,1); then sweep (1,1) + scans.
// half1: stream + fused (1,0);       then sweep (1,-1) + scans.
__global__ __launch_bounds__(NT, 4) void k_glcm(const float* __restrict__ x,
                                                uint32_t* __restrict__ gray,
                                                double* __restrict__ part) {
    __shared__ uint32_t hist[16384];    // 64 KB u8 H[256][256], swizzled words
    __shared__ double red[64];

    const int bid = blockIdx.x;
    const int half = (bid >> 3) & 1;                 // frame pair on same XCD (mod 8)
    const int f = ((bid >> 4) << 3) | (bid & 7);
    const int bq = f >> 3, fq = f & 7;
    const int tid = threadIdx.x, lane = tid & 63, wave = tid >> 6;

    const float* xb = x + ((size_t)bq * 24 + fq) * NPIX;   // channel stride 8*NPIX
    const float4* xc0 = reinterpret_cast<const float4*>(xb);
    const float4* xc1 = reinterpret_cast<const float4*>(xb + 8 * NPIX);
    const float4* xc2 = reinterpret_cast<const float4*>(xb + 16 * NPIX);
    uint32_t* gg = gray + (size_t)f * NQ4;

    uint4* h4 = reinterpret_cast<uint4*>(hist);
    const uint4 z4 = make_uint4(0u, 0u, 0u, 0u);
    #pragma unroll
    for (int i = 0; i < 8; ++i) h4[tid + (i << 9)] = z4;
    __syncthreads();

    // ---- stream in row-strip order: wave w owns rows [28w, 28w+28) ----
    uint32_t s1 = 0, s2 = 0;
    const int strip0 = wave * STRIP;
    if (lane < 56) {
        uint32_t prev = 0;
        for (int rr = 0; rr < STRIP; ++rr) {
            int m = (strip0 + rr) * ROWQ + lane;
            float4 av = xc0[m], bv = xc1[m], cv = xc2[m];
            uint32_t v0 = quant1(av.x + bv.x + cv.x);
            uint32_t v1 = quant1(av.y + bv.y + cv.y);
            uint32_t v2 = quant1(av.z + bv.z + cv.z);
            uint32_t v3 = quant1(av.w + bv.w + cv.w);
            uint32_t pk = v0 | (v1 << 8) | (v2 << 16) | (v3 << 24);
            gg[m] = pk;                              // both halves write same values
            if (half == 0) {
                s1 = udot4acc(pk, 0x01010101u, s1);
                s2 = udot4acc(pk, pk, s2);
                uint32_t nx = __shfl_down(pk, 1, 64);   // lane 55 unused below
                hist_inc(hist, pk & 0xffu, (pk >> 8) & 0xffu);
                hist_inc(hist, (pk >> 8) & 0xffu, (pk >> 16) & 0xffu);
                hist_inc(hist, (pk >> 16) & 0xffu, pk >> 24);
                if (lane < 55) hist_inc(hist, pk >> 24, nx & 0xffu);
            } else {
                if (rr > 0) {                        // (1,0): prev row vs this row
                    #pragma unroll
                    for (int k = 0; k < 4; ++k)
                        hist_inc(hist, (prev >> (8 * k)) & 0xffu, (pk >> (8 * k)) & 0xffu);
                }
                prev = pk;
            }
        }
    }
    __syncthreads();                                 // gg visible block-wide

    double conD = 0.0, disD = 0.0, homD = 0.0, asmD = 0.0;
    const double npA = 49952.0, npB = 49729.0;
    const double invA = 1.0 / npA, invB = 1.0 / npB;
    const double invA2 = 1.0 / (2.0 * npA * npA), invB2 = 1.0 / (2.0 * npB * npB);

    if (half == 1) {                                 // (1,0) strip-boundary fixups
        if (tid < 392) {                             // 7 boundaries x 56 dwords
            int w = tid / 56 + 1, c = tid % 56;
            uint32_t A = gg[(28 * w - 1) * ROWQ + c];
            uint32_t B = gg[(28 * w) * ROWQ + c];
            #pragma unroll
            for (int k = 0; k < 4; ++k)
                hist_inc(hist, (A >> (8 * k)) & 0xffu, (B >> (8 * k)) & 0xffu);
        }
        __syncthreads();
    }

    // scan first offset: (0,1) or (1,0), both np = 49952
    stats_scan(hist, tid, wave, lane, invA, invA2, conD, disD, homD, asmD);
    __syncthreads();
    #pragma unroll
    for (int i = 0; i < 8; ++i) h4[tid + (i << 9)] = z4;
    __syncthreads();

    // ---- second offset sweep over gg: (1,1) for half0, (1,-1) for half1 ----
    if (half == 0) {
        for (int it = 0; it < 25; ++it) {
            int m = it * NT + tid;
            int mc = (m < M10) ? m : (M10 - 1);      // clamp keeps shfl sources exact
            uint32_t A = gg[mc];
            uint32_t B = gg[mc + 56];
            uint32_t Bn = __shfl_down(B, 1, 64);
            uint32_t Bv = (B >> 8) | (Bn << 24);
            if (m < M10) {
                hist_inc(hist, A & 0xffu, Bv & 0xffu);
                hist_inc(hist, (A >> 8) & 0xffu, (Bv >> 8) & 0xffu);
                hist_inc(hist, (A >> 16) & 0xffu, (Bv >> 16) & 0xffu);
                if (lane != 63 && m % 56 != 55)
                    hist_inc(hist, A >> 24, Bv >> 24);
            }
        }
        if (tid < 195) {                             // lane-63 boundary fixup
            int m = tid * 64 + 63;
            if (m < M10 && m % 56 != 55)
                hist_inc(hist, gg[m] >> 24, gg[m + 57] & 0xffu);
        }
    } else {
        for (int it = 0; it < 25; ++it) {
            int m = it * NT + tid;
            int mc = (m < M10) ? m : (M10 - 1);
            uint32_t A = gg[mc];
            uint32_t B = gg[mc + 56];
            uint32_t Bp = __shfl_up(B, 1, 64);
            uint32_t Bv = (B << 8) | (Bp >> 24);
            if (m < M10) {
                if (lane != 0 && m % 56 != 0)
                    hist_inc(hist, A & 0xffu, Bv & 0xffu);
                hist_inc(hist, (A >> 8) & 0xffu, (Bv >> 8) & 0xffu);
                hist_inc(hist, (A >> 16) & 0xffu, (Bv >> 16) & 0xffu);
                hist_inc(hist, A >> 24, Bv >> 24);
            }
        }
        if (tid >= 1 && tid < 196) {                 // lane-0 boundary fixup
            int m = tid * 64;
            if (m < M10 && m % 56 != 0)
                hist_inc(hist, gg[m] & 0xffu, gg[m + 55] >> 24);
        }
    }
    __syncthreads();
    stats_scan(hist, tid, wave, lane, invB, invB2, conD, disD, homD, asmD);

    // ---- reduce 6 doubles -> per-block partials ----
    double vals[6] = {(double)s1, (double)s2, conD, disD, homD, asmD};
    #pragma unroll
    for (int off = 32; off; off >>= 1) {
        #pragma unroll
        for (int i = 0; i < 6; ++i) vals[i] += __shfl_down(vals[i], off, 64);
    }
    if (lane == 0) {
        #pragma unroll
        for (int i = 0; i < 6; ++i) red[wave * 8 + i] = vals[i];
    }
    __syncthreads();
    if (tid == 0) {
        #pragma unroll
        for (int i = 0; i < 6; ++i) {
            double t = red[i];
            for (int w = 1; w < NWAVE; ++w) t += red[w * 8 + i];
            part[(size_t)bid * 6 + i] = t;
        }
    }
}

// ---------------- Kernel 2: combine halves, finalize ----------------
__global__ __launch_bounds__(256) void k_final(const double* __restrict__ part,
                                               float* __restrict__ out) {
    int f = threadIdx.x;                          // 256 frames, 1 block
    int bid0 = ((f >> 3) << 4) + (f & 7);         // half0 block of frame f
    const double* p0 = part + (size_t)bid0 * 6;
    const double* p1 = p0 + 48;                   // half1 block = bid0 + 8
    double con = (p0[2] + p1[2]) * 0.25;
    double dis = (p0[3] + p1[3]) * 0.25;
    double hom = (p0[4] + p1[4]) * 0.25;
    double as  = (p0[5] + p1[5]) * 0.25;
    double N = (double)NPIX;
    double mean = p0[0] / N;
    double var = p0[1] / N - mean * mean;
    if (var < 0.0) var = 0.0;
    float* op = out + f * 6;
    op[0] = (float)sqrt(var);
    op[1] = (float)con;
    op[2] = (float)dis;
    op[3] = (float)hom;
    op[4] = (float)as;
    op[5] = (float)sqrt(as);
}

extern "C" void kernel_launch(void* const* d_in, const int* in_sizes, int n_in,
                              void* d_out, int out_size, void* d_ws, size_t ws_size,
                              hipStream_t stream) {
    const float* x = (const float*)d_in[0];
    float* out = (float*)d_out;
    uint32_t* gray = (uint32_t*)d_ws;                              // 12.8 MB
    double* part = (double*)((uint8_t*)d_ws + GRAY_BYTES);         // 512*6 doubles

    k_glcm<<<NFRAMES * 2, NT, 0, stream>>>(x, gray, part);
    k_final<<<1, 256, 0, stream>>>(part, out);
}